// Round 6
// baseline (226.799 us; speedup 1.0000x reference)
//
#include <hip/hip_runtime.h>

#define V_VOCAB 50000
#define K_DIM   300
#define NROWS   1024
#define LEN     64
#define NCG     1564    // col-groups of 32 per side: 1564*32 = 50048 >= 50000
#define KS      19      // k-steps of 16: covers k=0..303 (300 dims + bias@300)
#define RBLK    32      // row-chunks of 32: 32*32 = 1024 rows
#define LOG2E   1.44269504088896f

typedef __attribute__((ext_vector_type(8)))  short bf16x8;
typedef __attribute__((ext_vector_type(16))) float f32x16;

static __device__ __forceinline__ unsigned short f2bf(float f) {
    unsigned int u = __builtin_bit_cast(unsigned int, f);
    u = u + 0x7fffu + ((u >> 16) & 1u);   // RNE
    return (unsigned short)(u >> 16);
}

static __device__ __forceinline__ f32x16 zero16() {
    f32x16 z;
#pragma unroll
    for (int i = 0; i < 16; ++i) z[i] = 0.0f;
    return z;
}

// ---------------------------------------------------------------------------
// Kernel 1: samp_hid f32 [1024][300] -> bf16 B-fragment buffer for 32x32x16,
// pre-scaled by log2(e) so the GEMM epilogue is a bare exp2.
// Frag (rblk, ks): lane l holds Zs[rblk*32 + (l&31)][ks*16 + (l>>5)*8 + j].
// k==300 -> log2e (bias slot), k>300 -> 0.  623 KB total: L2/L1-resident.
__global__ void zbf_kernel(const float* __restrict__ z, unsigned short* __restrict__ zbf) {
    int t = blockIdx.x * 256 + threadIdx.x;      // 0..38911 = 32 rblk * 19 ks * 64 lanes
    int l    = t & 63;
    int rest = t >> 6;
    int ks   = rest % KS;
    int rblk = rest / KS;
    int row  = rblk * 32 + (l & 31);
    int k0   = ks * 16 + (l >> 5) * 8;
    unsigned short o[8];
#pragma unroll
    for (int j = 0; j < 8; ++j) {
        int k = k0 + j;
        float v = (k < K_DIM) ? z[row * K_DIM + k] * LOG2E
                              : ((k == K_DIM) ? LOG2E : 0.0f);
        o[j] = f2bf(v);
    }
    ushort4* p = (ushort4*)(zbf + (size_t)t * 8);
    p[0] = make_ushort4(o[0], o[1], o[2], o[3]);
    p[1] = make_ushort4(o[4], o[5], o[6], o[7]);
}

// ---------------------------------------------------------------------------
// Kernel 2 (streaming, no LDS): wave = one 32-col group over all 1024 rows.
// D[c][m] = log2e*(E[c].Z[m] + bias_c); partial[cg][m] = sum_c 2^D.
// Z b-frags read straight from global (L1/L2-resident, all 4 waves of a block
// read identical addresses). a[19]=76 VGPR, one f32x16 acc => ~115 VGPR.
__global__ void __launch_bounds__(256, 4)
gemm_kernel(const unsigned short* __restrict__ zbf,
            const float* __restrict__ emb_x,
            const float* __restrict__ emb_y,
            const float* __restrict__ bias_x,
            const float* __restrict__ bias_y,
            float* __restrict__ partial,
            float* __restrict__ lsesum,
            int accmode) {
    const int tid  = threadIdx.x;
    const int lane = tid & 63;
    const int wid  = blockIdx.x * 4 + (tid >> 6);   // 0..3127
    const int side = (wid >= NCG) ? 1 : 0;
    const int cg   = wid - side * NCG;
    const float* eg = side ? emb_y : emb_x;
    const float* bg = side ? bias_y : bias_x;

    // ---- load E a-fragments into registers: 32 cols/wave
    bf16x8 a[KS];
    {
        const int c  = cg * 32 + (lane & 31);
        const bool cv = (c < V_VOCAB);
        const float* erow = eg + (size_t)c * K_DIM;
        const int khi = (lane >> 5) * 8;
#pragma unroll
        for (int ks = 0; ks < KS; ++ks) {
            const int k0 = ks * 16 + khi;
            float f[8];
            if (k0 + 8 <= K_DIM) {
                float4 u  = cv ? *(const float4*)(erow + k0)     : make_float4(0, 0, 0, 0);
                float4 v2 = cv ? *(const float4*)(erow + k0 + 4) : make_float4(0, 0, 0, 0);
                f[0] = u.x;  f[1] = u.y;  f[2] = u.z;  f[3] = u.w;
                f[4] = v2.x; f[5] = v2.y; f[6] = v2.z; f[7] = v2.w;
            } else {
#pragma unroll
                for (int j = 0; j < 8; ++j) {
                    int k = k0 + j;
                    f[j] = (k < K_DIM) ? (cv ? erow[k] : 0.0f)
                         : (k == K_DIM ? (cv ? bg[c] : -3e38f) : 0.0f);
                }
            }
            bf16x8 t;
#pragma unroll
            for (int j = 0; j < 8; ++j) t[j] = (short)f2bf(f[j]);
            a[ks] = t;
        }
    }

    float* pout = partial + (size_t)wid * NROWS;
    float* lout = lsesum + side * NROWS;

    for (int rb = 0; rb < RBLK; ++rb) {
        const bf16x8* bp = (const bf16x8*)(zbf + (size_t)rb * KS * 512);
        f32x16 acc = zero16();
#pragma unroll
        for (int ks = 0; ks < KS; ++ks) {
            bf16x8 b = bp[ks * 64 + lane];
            acc = __builtin_amdgcn_mfma_f32_32x32x16_bf16(a[ks], b, acc, 0, 0, 0);
        }
        // epilogue: 2^D, sum over the wave's 32 vocab cols for each of 32 rows
        float s = 0.0f;
#pragma unroll
        for (int r = 0; r < 16; ++r) s += exp2f(acc[r]);
        s += __shfl_xor(s, 32, 64);
        if (accmode) { if (lane < 32) atomicAdd(lout + rb * 32 + lane, s); }
        else         { if (lane < 32) pout[rb * 32 + lane] = s; }

        if ((rb & 3) == 3) __builtin_amdgcn_s_barrier();   // phase-lock hint (L1 reuse)
    }
}

// ---------------------------------------------------------------------------
// Kernel 3a (partial mode): LSE[side][m] = log( sum_cg partial[cg][m] )
__global__ void lse_kernel(const float* __restrict__ partial, float* __restrict__ lse) {
    __shared__ float red[1024];
    int side = blockIdx.x >> 4;                 // 0..1
    int mg   = blockIdx.x & 15;                 // 16 groups of 64 rows
    int m    = mg * 64 + (threadIdx.x & 63);
    int sg   = threadIdx.x >> 6;                // 0..15 cg-stripes
    const float* p = partial + (size_t)side * NCG * NROWS;
    float s = 0.0f;
    for (int cg = sg; cg < NCG; cg += 16)
        s += p[(size_t)cg * NROWS + m];
    red[threadIdx.x] = s;
    __syncthreads();
    if (threadIdx.x < 64) {
        float t = 0.0f;
#pragma unroll
        for (int j = 0; j < 16; ++j) t += red[threadIdx.x + 64 * j];
        lse[side * NROWS + mg * 64 + threadIdx.x] = logf(t);
    }
}

// Kernel 3b (atomic mode): in-place log of accumulated sums
__global__ void lse_log_kernel(float* __restrict__ lsesum) {
    int g = blockIdx.x * 1024 + threadIdx.x;
    if (g < 2 * NROWS) lsesum[g] = logf(lsesum[g]);
}

// ---------------------------------------------------------------------------
// Kernel 4: per (b, side, pos-half): g = sum_{valid pos in half} e_t ;
// gdpart[(side*1024+b)*2+half] = ct*LSE - (z_b . g + sum bias_t)
__global__ void gatherdot_kernel(const float* __restrict__ z,
                                 const int* __restrict__ tok_x, const int* __restrict__ tok_y,
                                 const float* __restrict__ emb_x, const float* __restrict__ emb_y,
                                 const float* __restrict__ bias_x, const float* __restrict__ bias_y,
                                 const float* __restrict__ lse, float* __restrict__ gdpart) {
    __shared__ float gs[304];
    const int b = blockIdx.x, side = blockIdx.y & 1, half = blockIdx.y >> 1;
    const int tid = threadIdx.x;
    const int* tokp = (side ? tok_y : tok_x) + b * LEN + half * 32;
    const float* eg = side ? emb_y : emb_x;
    if (tid < K_DIM) {
        float g0 = 0.0f, g1 = 0.0f, g2 = 0.0f, g3 = 0.0f;
#pragma unroll 4
        for (int pos = 0; pos < 32; pos += 4) {
            int t0 = tokp[pos], t1 = tokp[pos + 1], t2 = tokp[pos + 2], t3 = tokp[pos + 3];
            if (t0) g0 += eg[(size_t)t0 * K_DIM + tid];
            if (t1) g1 += eg[(size_t)t1 * K_DIM + tid];
            if (t2) g2 += eg[(size_t)t2 * K_DIM + tid];
            if (t3) g3 += eg[(size_t)t3 * K_DIM + tid];
        }
        gs[tid] = (g0 + g1) + (g2 + g3);
    }
    __syncthreads();
    if (tid < 64) {
        const float* bg = side ? bias_y : bias_x;
        float dp = 0.0f;
#pragma unroll
        for (int i = 0; i < 5; ++i) {
            int d = tid + i * 64;
            if (d < K_DIM) dp += z[(size_t)b * K_DIM + d] * gs[d];
        }
        int t = (tid < 32) ? tokp[tid] : 0;
        float bs = t ? bg[t] : 0.0f;
        float ct = t ? 1.0f : 0.0f;
#pragma unroll
        for (int off = 32; off > 0; off >>= 1) {
            dp += __shfl_xor(dp, off, 64);
            bs += __shfl_xor(bs, off, 64);
            ct += __shfl_xor(ct, off, 64);
        }
        if (tid == 0)
            gdpart[((size_t)side * NROWS + b) * 2 + half] =
                ct * lse[side * NROWS + b] - dp - bs;
    }
}

// ---------------------------------------------------------------------------
// Kernel 5: out = mean over b of sum of the 4 gdpart terms
__global__ void finalize_kernel(const float* __restrict__ gdpart, float* __restrict__ out) {
    __shared__ float r16[16];
    int i = threadIdx.x;   // 0..1023
    float v = gdpart[i * 2] + gdpart[i * 2 + 1]
            + gdpart[(NROWS + i) * 2] + gdpart[(NROWS + i) * 2 + 1];
#pragma unroll
    for (int off = 32; off > 0; off >>= 1) v += __shfl_xor(v, off, 64);
    if ((i & 63) == 0) r16[i >> 6] = v;
    __syncthreads();
    if (i < 64) {
        float x = (i < 16) ? r16[i] : 0.0f;
#pragma unroll
        for (int off = 8; off > 0; off >>= 1) x += __shfl_xor(x, off, 64);
        if (i == 0) out[0] = x * (1.0f / 1024.0f);
    }
}

// ---------------------------------------------------------------------------
extern "C" void kernel_launch(void* const* d_in, const int* in_sizes, int n_in,
                              void* d_out, int out_size, void* d_ws, size_t ws_size,
                              hipStream_t stream) {
    const float* z      = (const float*)d_in[0];
    const int*   tok_x  = (const int*)d_in[1];
    const int*   tok_y  = (const int*)d_in[2];
    const float* emb_x  = (const float*)d_in[3];
    const float* emb_y  = (const float*)d_in[4];
    const float* bias_x = (const float*)d_in[5];
    const float* bias_y = (const float*)d_in[6];
    float* out = (float*)d_out;

    char* ws = (char*)d_ws;
    const size_t ZBF_B  = 622592;                       // 38912 frags * 16 B
    const size_t PART_B = (size_t)2 * NCG * NROWS * 4;  // 12,812,288 B
    const size_t need   = ZBF_B + PART_B + 8192 + 16384;

    unsigned short* zbf = (unsigned short*)ws;
    zbf_kernel<<<152, 256, 0, stream>>>(z, zbf);

    if (ws_size >= need) {
        float* partial = (float*)(ws + ZBF_B);
        float* lse     = (float*)(ws + ZBF_B + PART_B);
        float* gdpart  = (float*)(ws + ZBF_B + PART_B + 8192);
        gemm_kernel<<<782, 256, 0, stream>>>(zbf, emb_x, emb_y, bias_x, bias_y,
                                             partial, lse /*unused*/, 0);
        lse_kernel<<<32, 1024, 0, stream>>>(partial, lse);
        gatherdot_kernel<<<dim3(NROWS, 4), 320, 0, stream>>>(z, tok_x, tok_y, emb_x, emb_y,
                                                             bias_x, bias_y, lse, gdpart);
        finalize_kernel<<<1, 1024, 0, stream>>>(gdpart, out);
    } else {
        // compact fallback: accumulate exp-sums with float atomics (error << tol)
        float* lse    = (float*)(ws + ZBF_B);
        float* gdpart = (float*)(ws + ZBF_B + 8192);
        hipMemsetAsync(lse, 0, 8192, stream);
        gemm_kernel<<<782, 256, 0, stream>>>(zbf, emb_x, emb_y, bias_x, bias_y,
                                             gdpart /*unused*/, lse, 1);
        lse_log_kernel<<<2, 1024, 0, stream>>>(lse);
        gatherdot_kernel<<<dim3(NROWS, 4), 320, 0, stream>>>(z, tok_x, tok_y, emb_x, emb_y,
                                                             bias_x, bias_y, lse, gdpart);
        finalize_kernel<<<1, 1024, 0, stream>>>(gdpart, out);
    }
}

// Round 7
// 182.206 us; speedup vs baseline: 1.2447x; 1.2447x over previous
//
#include <hip/hip_runtime.h>

#define V_VOCAB 50000
#define K_DIM   300
#define NROWS   1024
#define LEN     64
#define NBC     392     // col-blocks per side: 392*128 = 50176 >= 50000
#define NCG     1568    // col-groups (waves of 32 cols) per side = NBC*4
#define KS      19      // k-steps of 16: covers k=0..303 (300 dims + bias@300)
#define PASSES  32      // 32 passes x 32 rows = 1024 rows
#define LOG2E   1.44269504088896f

typedef __attribute__((ext_vector_type(8)))  short bf16x8;
typedef __attribute__((ext_vector_type(16))) float f32x16;

static __device__ __forceinline__ unsigned short f2bf(float f) {
    unsigned int u = __builtin_bit_cast(unsigned int, f);
    u = u + 0x7fffu + ((u >> 16) & 1u);   // RNE
    return (unsigned short)(u >> 16);
}

static __device__ __forceinline__ f32x16 zero16() {
    f32x16 z;
#pragma unroll
    for (int i = 0; i < 16; ++i) z[i] = 0.0f;
    return z;
}

static __device__ __forceinline__ void gload_lds16(const void* g, void* l) {
    __builtin_amdgcn_global_load_lds((const __attribute__((address_space(1))) void*)g,
                                     (__attribute__((address_space(3))) void*)l, 16, 0, 0);
}

// ---------------------------------------------------------------------------
// Kernel 1: samp_hid f32 [1024][300] -> bf16 B-fragment buffer for 32x32x16,
// pre-scaled by log2(e) so the GEMM epilogue is a bare exp2.
// Frag (rblk, ks): lane l holds Zs[rblk*32 + (l&31)][ks*16 + (l>>5)*8 + j].
// k==300 -> log2e (bias slot), k>300 -> 0.  623 KB total: L2-resident.
__global__ void zbf_kernel(const float* __restrict__ z, unsigned short* __restrict__ zbf) {
    int t = blockIdx.x * 256 + threadIdx.x;      // 0..38911 = 32 rblk * 19 ks * 64 lanes
    int l    = t & 63;
    int rest = t >> 6;
    int ks   = rest % KS;
    int rblk = rest / KS;
    int row  = rblk * 32 + (l & 31);
    int k0   = ks * 16 + (l >> 5) * 8;
    unsigned short o[8];
#pragma unroll
    for (int j = 0; j < 8; ++j) {
        int k = k0 + j;
        float v = (k < K_DIM) ? z[row * K_DIM + k] * LOG2E
                              : ((k == K_DIM) ? LOG2E : 0.0f);
        o[j] = f2bf(v);
    }
    ushort4* p = (ushort4*)(zbf + (size_t)t * 8);
    p[0] = make_ushort4(o[0], o[1], o[2], o[3]);
    p[1] = make_ushort4(o[4], o[5], o[6], o[7]);
}

// ---------------------------------------------------------------------------
// Kernel 2: D[c][m] = log2e*(E[c].Z[m] + bias_c); partial[cg][m] = sum_c 2^D.
// R4's proven no-spill shape (32 cols/wave, a[19]=76 VGPR) with 32-row slabs:
// LDS 38,912 B/block -> 4 blocks/CU, grid 784 = single occupancy round.
// Per pass: issue 5 gload_lds for p+1, vmcnt(5), barrier, 19 ds_read : 19 MFMA
// (2 chains), barrier. 2 blocks/CU more than R4 + issue-early prefetch.
__global__ void __launch_bounds__(256, 2)
gemm_kernel(const unsigned short* __restrict__ zbf,
            const float* __restrict__ emb_x,
            const float* __restrict__ emb_y,
            const float* __restrict__ bias_x,
            const float* __restrict__ bias_y,
            float* __restrict__ partial,
            float* __restrict__ lsesum,
            int accmode) {
    __shared__ unsigned short Zs[2][9728];   // 2 x 19,456 B = 38,912 B

    const int tid  = threadIdx.x;
    const int lane = tid & 63;
    const int w    = tid >> 6;               // 0..3
    const int side = blockIdx.y;
    const int bc   = blockIdx.x;
    const float* eg = side ? emb_y : emb_x;
    const float* bg = side ? bias_y : bias_x;

    // ---- start staging pass 0 while we load E fragments (5 issues/wave,
    //      wave 3 duplicates chunk 18 so the per-wave count is uniform)
    {
        const unsigned short* src = zbf;
#pragma unroll
        for (int i = 0; i < 5; ++i) {
            int q = w * 5 + i;
            if (q > 18) q = 18;              // idempotent dup (wave 3 only)
            gload_lds16(src + (size_t)q * 512 + lane * 8, &Zs[0][q * 512]);
        }
    }

    // ---- load E a-fragments into registers (once per wave): 32 cols/wave
    bf16x8 a[KS];
    {
        const int c  = bc * 128 + w * 32 + (lane & 31);
        const bool cv = (c < V_VOCAB);
        const float* erow = eg + (size_t)c * K_DIM;
        const int khi = (lane >> 5) * 8;
#pragma unroll
        for (int ks = 0; ks < KS; ++ks) {
            const int k0 = ks * 16 + khi;
            float f[8];
            if (k0 + 8 <= K_DIM) {
                float4 u  = cv ? *(const float4*)(erow + k0)     : make_float4(0, 0, 0, 0);
                float4 v2 = cv ? *(const float4*)(erow + k0 + 4) : make_float4(0, 0, 0, 0);
                f[0] = u.x;  f[1] = u.y;  f[2] = u.z;  f[3] = u.w;
                f[4] = v2.x; f[5] = v2.y; f[6] = v2.z; f[7] = v2.w;
            } else {
#pragma unroll
                for (int j = 0; j < 8; ++j) {
                    int k = k0 + j;
                    f[j] = (k < K_DIM) ? (cv ? erow[k] : 0.0f)
                         : (k == K_DIM ? (cv ? bg[c] : -3e38f) : 0.0f);
                }
            }
            bf16x8 t;
#pragma unroll
            for (int j = 0; j < 8; ++j) t[j] = (short)f2bf(f[j]);
            a[ks] = t;
        }
    }

    float* pout = partial + ((size_t)side * NCG + (size_t)bc * 4 + w) * NROWS;
    float* lout = lsesum + side * NROWS;

    int buf = 0;
    for (int p = 0; p < PASSES; ++p) {
        if (p < PASSES - 1) {
            const unsigned short* src = zbf + (size_t)(p + 1) * 9728;
#pragma unroll
            for (int i = 0; i < 5; ++i) {
                int q = w * 5 + i;
                if (q > 18) q = 18;
                gload_lds16(src + (size_t)q * 512 + lane * 8, &Zs[buf ^ 1][q * 512]);
            }
            // own-wave outstanding <= 10; oldest 5 are pass p's -> wait them
            asm volatile("s_waitcnt vmcnt(5)" ::: "memory");
        } else {
            asm volatile("s_waitcnt vmcnt(0)" ::: "memory");
        }
        __builtin_amdgcn_s_barrier();          // all waves' slices of pass p landed
        __builtin_amdgcn_sched_barrier(0);

        const unsigned short* zb = &Zs[buf][0];
        f32x16 accE = zero16(), accO = zero16();
#pragma unroll
        for (int ks = 0; ks < KS; ks += 2) {
            bf16x8 b0 = *(const bf16x8*)(zb + ((size_t)ks * 64 + lane) * 8);
            accE = __builtin_amdgcn_mfma_f32_32x32x16_bf16(a[ks], b0, accE, 0, 0, 0);
            if (ks + 1 < KS) {
                bf16x8 b1 = *(const bf16x8*)(zb + ((size_t)(ks + 1) * 64 + lane) * 8);
                accO = __builtin_amdgcn_mfma_f32_32x32x16_bf16(a[ks + 1], b1, accO, 0, 0, 0);
            }
        }

        // epilogue: 2^D, sum the wave's 32 vocab cols for each of 32 rows
        float s = 0.0f;
#pragma unroll
        for (int r = 0; r < 16; ++r) s += exp2f(accE[r] + accO[r]);
        s += __shfl_xor(s, 32, 64);
        if (accmode) { if (lane < 32) atomicAdd(lout + p * 32 + lane, s); }
        else         { if (lane < 32) pout[p * 32 + lane] = s; }

        __builtin_amdgcn_s_barrier();          // all waves done reading buf
        buf ^= 1;
    }
}

// ---------------------------------------------------------------------------
// Kernel 3a (partial mode): LSE[side][m] = log( sum_cg partial[cg][m] )
__global__ void lse_kernel(const float* __restrict__ partial, float* __restrict__ lse) {
    __shared__ float red[1024];
    int side = blockIdx.x >> 4;                 // 0..1
    int mg   = blockIdx.x & 15;                 // 16 groups of 64 rows
    int m    = mg * 64 + (threadIdx.x & 63);
    int sg   = threadIdx.x >> 6;                // 0..15 cg-stripes
    const float* p = partial + (size_t)side * NCG * NROWS;
    float s = 0.0f;
    for (int cg = sg; cg < NCG; cg += 16)
        s += p[(size_t)cg * NROWS + m];
    red[threadIdx.x] = s;
    __syncthreads();
    if (threadIdx.x < 64) {
        float t = 0.0f;
#pragma unroll
        for (int j = 0; j < 16; ++j) t += red[threadIdx.x + 64 * j];
        lse[side * NROWS + mg * 64 + threadIdx.x] = logf(t);
    }
}

// Kernel 3b (atomic mode): in-place log of accumulated sums
__global__ void lse_log_kernel(float* __restrict__ lsesum) {
    int g = blockIdx.x * 1024 + threadIdx.x;
    if (g < 2 * NROWS) lsesum[g] = logf(lsesum[g]);
}

// ---------------------------------------------------------------------------
// Kernel 4: per (b, side, pos-half): g = sum_{valid pos in half} e_t ;
// gdpart[(side*1024+b)*2+half] = ct*LSE - (z_b . g + sum bias_t)
__global__ void gatherdot_kernel(const float* __restrict__ z,
                                 const int* __restrict__ tok_x, const int* __restrict__ tok_y,
                                 const float* __restrict__ emb_x, const float* __restrict__ emb_y,
                                 const float* __restrict__ bias_x, const float* __restrict__ bias_y,
                                 const float* __restrict__ lse, float* __restrict__ gdpart) {
    __shared__ float gs[304];
    const int b = blockIdx.x, side = blockIdx.y & 1, half = blockIdx.y >> 1;
    const int tid = threadIdx.x;
    const int* tokp = (side ? tok_y : tok_x) + b * LEN + half * 32;
    const float* eg = side ? emb_y : emb_x;
    if (tid < K_DIM) {
        float g0 = 0.0f, g1 = 0.0f, g2 = 0.0f, g3 = 0.0f;
#pragma unroll 4
        for (int pos = 0; pos < 32; pos += 4) {
            int t0 = tokp[pos], t1 = tokp[pos + 1], t2 = tokp[pos + 2], t3 = tokp[pos + 3];
            if (t0) g0 += eg[(size_t)t0 * K_DIM + tid];
            if (t1) g1 += eg[(size_t)t1 * K_DIM + tid];
            if (t2) g2 += eg[(size_t)t2 * K_DIM + tid];
            if (t3) g3 += eg[(size_t)t3 * K_DIM + tid];
        }
        gs[tid] = (g0 + g1) + (g2 + g3);
    }
    __syncthreads();
    if (tid < 64) {
        const float* bg = side ? bias_y : bias_x;
        float dp = 0.0f;
#pragma unroll
        for (int i = 0; i < 5; ++i) {
            int d = tid + i * 64;
            if (d < K_DIM) dp += z[(size_t)b * K_DIM + d] * gs[d];
        }
        int t = (tid < 32) ? tokp[tid] : 0;
        float bs = t ? bg[t] : 0.0f;
        float ct = t ? 1.0f : 0.0f;
#pragma unroll
        for (int off = 32; off > 0; off >>= 1) {
            dp += __shfl_xor(dp, off, 64);
            bs += __shfl_xor(bs, off, 64);
            ct += __shfl_xor(ct, off, 64);
        }
        if (tid == 0)
            gdpart[((size_t)side * NROWS + b) * 2 + half] =
                ct * lse[side * NROWS + b] - dp - bs;
    }
}

// ---------------------------------------------------------------------------
// Kernel 5: out = mean over b of sum of the 4 gdpart terms
__global__ void finalize_kernel(const float* __restrict__ gdpart, float* __restrict__ out) {
    __shared__ float r16[16];
    int i = threadIdx.x;   // 0..1023
    float v = gdpart[i * 2] + gdpart[i * 2 + 1]
            + gdpart[(NROWS + i) * 2] + gdpart[(NROWS + i) * 2 + 1];
#pragma unroll
    for (int off = 32; off > 0; off >>= 1) v += __shfl_xor(v, off, 64);
    if ((i & 63) == 0) r16[i >> 6] = v;
    __syncthreads();
    if (i < 64) {
        float x = (i < 16) ? r16[i] : 0.0f;
#pragma unroll
        for (int off = 8; off > 0; off >>= 1) x += __shfl_xor(x, off, 64);
        if (i == 0) out[0] = x * (1.0f / 1024.0f);
    }
}

// ---------------------------------------------------------------------------
extern "C" void kernel_launch(void* const* d_in, const int* in_sizes, int n_in,
                              void* d_out, int out_size, void* d_ws, size_t ws_size,
                              hipStream_t stream) {
    const float* z      = (const float*)d_in[0];
    const int*   tok_x  = (const int*)d_in[1];
    const int*   tok_y  = (const int*)d_in[2];
    const float* emb_x  = (const float*)d_in[3];
    const float* emb_y  = (const float*)d_in[4];
    const float* bias_x = (const float*)d_in[5];
    const float* bias_y = (const float*)d_in[6];
    float* out = (float*)d_out;

    char* ws = (char*)d_ws;
    const size_t ZBF_B  = 622592;                       // 38912 frags * 16 B
    const size_t PART_B = (size_t)2 * NCG * NROWS * 4;  // 12,845,056 B
    const size_t need   = ZBF_B + PART_B + 8192 + 16384;

    unsigned short* zbf = (unsigned short*)ws;
    zbf_kernel<<<152, 256, 0, stream>>>(z, zbf);

    if (ws_size >= need) {
        float* partial = (float*)(ws + ZBF_B);
        float* lse     = (float*)(ws + ZBF_B + PART_B);
        float* gdpart  = (float*)(ws + ZBF_B + PART_B + 8192);
        gemm_kernel<<<dim3(NBC, 2), 256, 0, stream>>>(zbf, emb_x, emb_y, bias_x, bias_y,
                                                      partial, lse /*unused*/, 0);
        lse_kernel<<<32, 1024, 0, stream>>>(partial, lse);
        gatherdot_kernel<<<dim3(NROWS, 4), 320, 0, stream>>>(z, tok_x, tok_y, emb_x, emb_y,
                                                             bias_x, bias_y, lse, gdpart);
        finalize_kernel<<<1, 1024, 0, stream>>>(gdpart, out);
    } else {
        // compact fallback: accumulate exp-sums with float atomics (error << tol)
        float* lse    = (float*)(ws + ZBF_B);
        float* gdpart = (float*)(ws + ZBF_B + 8192);
        hipMemsetAsync(lse, 0, 8192, stream);
        gemm_kernel<<<dim3(NBC, 2), 256, 0, stream>>>(zbf, emb_x, emb_y, bias_x, bias_y,
                                                      gdpart /*unused*/, lse, 1);
        lse_log_kernel<<<2, 1024, 0, stream>>>(lse);
        gatherdot_kernel<<<dim3(NROWS, 4), 320, 0, stream>>>(z, tok_x, tok_y, emb_x, emb_y,
                                                             bias_x, bias_y, lse, gdpart);
        finalize_kernel<<<1, 1024, 0, stream>>>(gdpart, out);
    }
}

// Round 8
// 169.074 us; speedup vs baseline: 1.3414x; 1.0777x over previous
//
#include <hip/hip_runtime.h>

#define V_VOCAB 50000
#define K_DIM   300
#define NROWS   1024
#define LEN     64
#define NBC     392     // col-blocks per side: 392*128 = 50176 >= 50000
#define NCG     1568    // col-groups (waves of 32 cols) per side = NBC*4
#define KS      19      // k-steps of 16: covers k=0..303 (300 dims + bias@300)
#define PASSES  16      // 16 passes x 64 rows = 1024 rows
#define LOG2E   1.44269504088896f

typedef __attribute__((ext_vector_type(8)))  short bf16x8;
typedef __attribute__((ext_vector_type(16))) float f32x16;

static __device__ __forceinline__ unsigned short f2bf(float f) {
    unsigned int u = __builtin_bit_cast(unsigned int, f);
    u = u + 0x7fffu + ((u >> 16) & 1u);   // RNE
    return (unsigned short)(u >> 16);
}

static __device__ __forceinline__ f32x16 zero16() {
    f32x16 z;
#pragma unroll
    for (int i = 0; i < 16; ++i) z[i] = 0.0f;
    return z;
}

static __device__ __forceinline__ float exp2_hw(float x) {
    float r;
    asm volatile("v_exp_f32 %0, %1" : "=v"(r) : "v"(x));
    return r;
}

static __device__ __forceinline__ void gload_lds16(const void* g, void* l) {
    __builtin_amdgcn_global_load_lds((const __attribute__((address_space(1))) void*)g,
                                     (__attribute__((address_space(3))) void*)l, 16, 0, 0);
}

// ---------------------------------------------------------------------------
// Kernel 1: samp_hid f32 [1024][300] -> bf16 B-fragment buffer for 32x32x16,
// pre-scaled by log2(e) so the GEMM epilogue is a bare v_exp_f32.
// Frag (rblk, ks): lane l holds Zs[rblk*32 + (l&31)][ks*16 + (l>>5)*8 + j].
// k==300 -> log2e (bias slot), k>300 -> 0.  623 KB total: L2-resident.
__global__ void zbf_kernel(const float* __restrict__ z, unsigned short* __restrict__ zbf) {
    int t = blockIdx.x * 256 + threadIdx.x;      // 0..38911 = 32 rblk * 19 ks * 64 lanes
    int l    = t & 63;
    int rest = t >> 6;
    int ks   = rest % KS;
    int rblk = rest / KS;
    int row  = rblk * 32 + (l & 31);
    int k0   = ks * 16 + (l >> 5) * 8;
    unsigned short o[8];
#pragma unroll
    for (int j = 0; j < 8; ++j) {
        int k = k0 + j;
        float v = (k < K_DIM) ? z[row * K_DIM + k] * LOG2E
                              : ((k == K_DIM) ? LOG2E : 0.0f);
        o[j] = f2bf(v);
    }
    ushort4* p = (ushort4*)(zbf + (size_t)t * 8);
    p[0] = make_ushort4(o[0], o[1], o[2], o[3]);
    p[1] = make_ushort4(o[4], o[5], o[6], o[7]);
}

// ---------------------------------------------------------------------------
// Kernel 2: D[c][m] = log2e*(E[c].Z[m] + bias_c); partial[cg][m] = sum_c 2^D.
// R4 geometry (proven no-spill): 32 cols/wave (a[19]=76 VGPR), 4-wave blocks,
// 64-row slabs dbuf in LDS (77,824 B -> 2 blocks/CU). Changes vs R4:
// ONE barrier per pass, 4 MFMA accumulator chains, hw exp2.
__global__ void __launch_bounds__(256, 2)
gemm_kernel(const unsigned short* __restrict__ zbf,
            const float* __restrict__ emb_x,
            const float* __restrict__ emb_y,
            const float* __restrict__ bias_x,
            const float* __restrict__ bias_y,
            float* __restrict__ partial,
            float* __restrict__ lsesum,
            int accmode) {
    __shared__ unsigned short Zs[2][19456];   // 2 x 38,912 B = 77,824 B

    const int tid  = threadIdx.x;
    const int lane = tid & 63;
    const int w    = tid >> 6;               // 0..3
    const int side = blockIdx.y;
    const int bc   = blockIdx.x;
    const float* eg = side ? emb_y : emb_x;
    const float* bg = side ? bias_y : bias_x;

    // ---- start staging pass 0 while we load E fragments (10 issues/wave;
    //      38 chunks of 512 shorts; waves 3's extra two duplicate 30,31)
    {
        const unsigned short* src = zbf;
#pragma unroll
        for (int i = 0; i < 10; ++i) {
            int q = w * 10 + i;
            if (q >= 38) q -= 8;             // idempotent dup
            gload_lds16(src + (size_t)q * 512 + lane * 8, &Zs[0][q * 512]);
        }
    }

    // ---- load E a-fragments into registers (once per wave): 32 cols/wave
    bf16x8 a[KS];
    {
        const int c  = bc * 128 + w * 32 + (lane & 31);
        const bool cv = (c < V_VOCAB);
        const float* erow = eg + (size_t)c * K_DIM;
        const int khi = (lane >> 5) * 8;
#pragma unroll
        for (int ks = 0; ks < KS; ++ks) {
            const int k0 = ks * 16 + khi;
            float f[8];
            if (k0 + 8 <= K_DIM) {
                float4 u  = cv ? *(const float4*)(erow + k0)     : make_float4(0, 0, 0, 0);
                float4 v2 = cv ? *(const float4*)(erow + k0 + 4) : make_float4(0, 0, 0, 0);
                f[0] = u.x;  f[1] = u.y;  f[2] = u.z;  f[3] = u.w;
                f[4] = v2.x; f[5] = v2.y; f[6] = v2.z; f[7] = v2.w;
            } else {
#pragma unroll
                for (int j = 0; j < 8; ++j) {
                    int k = k0 + j;
                    f[j] = (k < K_DIM) ? (cv ? erow[k] : 0.0f)
                         : (k == K_DIM ? (cv ? bg[c] : -3e38f) : 0.0f);
                }
            }
            bf16x8 t;
#pragma unroll
            for (int j = 0; j < 8; ++j) t[j] = (short)f2bf(f[j]);
            a[ks] = t;
        }
    }

    float* pout = partial + ((size_t)side * NCG + (size_t)bc * 4 + w) * NROWS;
    float* lout = lsesum + side * NROWS;

    // prologue: finish pass-0 staging
    asm volatile("s_waitcnt vmcnt(0)" ::: "memory");
    __builtin_amdgcn_s_barrier();

    int buf = 0;
    for (int p = 0; p < PASSES; ++p) {
        // issue next slab's loads early (land during this pass's compute)
        if (p < PASSES - 1) {
            const unsigned short* src = zbf + (size_t)(p + 1) * 19456;
#pragma unroll
            for (int i = 0; i < 10; ++i) {
                int q = w * 10 + i;
                if (q >= 38) q -= 8;
                gload_lds16(src + (size_t)q * 512 + lane * 8, &Zs[buf ^ 1][q * 512]);
            }
        }

        const unsigned short* zb = &Zs[buf][0];
        // 4 accumulator chains: {row-block 0, row-block 1} x {even ks, odd ks}
        f32x16 a0e = zero16(), a0o = zero16(), a1e = zero16(), a1o = zero16();
#pragma unroll
        for (int ks = 0; ks < KS; ks += 2) {
            bf16x8 b0 = *(const bf16x8*)(zb + ((size_t)ks * 64 + lane) * 8);
            a0e = __builtin_amdgcn_mfma_f32_32x32x16_bf16(a[ks], b0, a0e, 0, 0, 0);
            bf16x8 b1 = *(const bf16x8*)(zb + ((size_t)(KS + ks) * 64 + lane) * 8);
            a1e = __builtin_amdgcn_mfma_f32_32x32x16_bf16(a[ks], b1, a1e, 0, 0, 0);
            if (ks + 1 < KS) {
                bf16x8 c0 = *(const bf16x8*)(zb + ((size_t)(ks + 1) * 64 + lane) * 8);
                a0o = __builtin_amdgcn_mfma_f32_32x32x16_bf16(a[ks + 1], c0, a0o, 0, 0, 0);
                bf16x8 c1 = *(const bf16x8*)(zb + ((size_t)(KS + ks + 1) * 64 + lane) * 8);
                a1o = __builtin_amdgcn_mfma_f32_32x32x16_bf16(a[ks + 1], c1, a1o, 0, 0, 0);
            }
        }

        // epilogue: 2^(D), per-lane sum over the wave's 32 cols, cross-half add
        float s0 = 0.0f, s1 = 0.0f;
#pragma unroll
        for (int r = 0; r < 16; ++r) {
            s0 += exp2_hw(a0e[r] + a0o[r]);
            s1 += exp2_hw(a1e[r] + a1o[r]);
        }
        s0 += __shfl_xor(s0, 32, 64);
        s1 += __shfl_xor(s1, 32, 64);
        float val = (lane < 32) ? s0 : s1;
        if (accmode) { if (lane < 64) atomicAdd(lout + p * 64 + lane, val); }
        else         { pout[p * 64 + lane] = val; }

        // single sync point: own stage-loads drained, then block-wide barrier
        asm volatile("s_waitcnt vmcnt(0)" ::: "memory");
        __builtin_amdgcn_s_barrier();
        buf ^= 1;
    }
}

// ---------------------------------------------------------------------------
// Kernel 3a (partial mode): LSE[side][m] = log( sum_cg partial[cg][m] )
__global__ void lse_kernel(const float* __restrict__ partial, float* __restrict__ lse) {
    __shared__ float red[1024];
    int side = blockIdx.x >> 4;                 // 0..1
    int mg   = blockIdx.x & 15;                 // 16 groups of 64 rows
    int m    = mg * 64 + (threadIdx.x & 63);
    int sg   = threadIdx.x >> 6;                // 0..15 cg-stripes
    const float* p = partial + (size_t)side * NCG * NROWS;
    float s = 0.0f;
    for (int cg = sg; cg < NCG; cg += 16)
        s += p[(size_t)cg * NROWS + m];
    red[threadIdx.x] = s;
    __syncthreads();
    if (threadIdx.x < 64) {
        float t = 0.0f;
#pragma unroll
        for (int j = 0; j < 16; ++j) t += red[threadIdx.x + 64 * j];
        lse[side * NROWS + mg * 64 + threadIdx.x] = logf(t);
    }
}

// Kernel 3b (atomic mode): in-place log of accumulated sums
__global__ void lse_log_kernel(float* __restrict__ lsesum) {
    int g = blockIdx.x * 1024 + threadIdx.x;
    if (g < 2 * NROWS) lsesum[g] = logf(lsesum[g]);
}

// ---------------------------------------------------------------------------
// Kernel 4: per (b, side, pos-half): g = sum_{valid pos in half} e_t ;
// gdpart[(side*1024+b)*2+half] = ct*LSE - (z_b . g + sum bias_t)
__global__ void gatherdot_kernel(const float* __restrict__ z,
                                 const int* __restrict__ tok_x, const int* __restrict__ tok_y,
                                 const float* __restrict__ emb_x, const float* __restrict__ emb_y,
                                 const float* __restrict__ bias_x, const float* __restrict__ bias_y,
                                 const float* __restrict__ lse, float* __restrict__ gdpart) {
    __shared__ float gs[304];
    const int b = blockIdx.x, side = blockIdx.y & 1, half = blockIdx.y >> 1;
    const int tid = threadIdx.x;
    const int* tokp = (side ? tok_y : tok_x) + b * LEN + half * 32;
    const float* eg = side ? emb_y : emb_x;
    if (tid < K_DIM) {
        float g0 = 0.0f, g1 = 0.0f, g2 = 0.0f, g3 = 0.0f;
#pragma unroll 4
        for (int pos = 0; pos < 32; pos += 4) {
            int t0 = tokp[pos], t1 = tokp[pos + 1], t2 = tokp[pos + 2], t3 = tokp[pos + 3];
            if (t0) g0 += eg[(size_t)t0 * K_DIM + tid];
            if (t1) g1 += eg[(size_t)t1 * K_DIM + tid];
            if (t2) g2 += eg[(size_t)t2 * K_DIM + tid];
            if (t3) g3 += eg[(size_t)t3 * K_DIM + tid];
        }
        gs[tid] = (g0 + g1) + (g2 + g3);
    }
    __syncthreads();
    if (tid < 64) {
        const float* bg = side ? bias_y : bias_x;
        float dp = 0.0f;
#pragma unroll
        for (int i = 0; i < 5; ++i) {
            int d = tid + i * 64;
            if (d < K_DIM) dp += z[(size_t)b * K_DIM + d] * gs[d];
        }
        int t = (tid < 32) ? tokp[tid] : 0;
        float bs = t ? bg[t] : 0.0f;
        float ct = t ? 1.0f : 0.0f;
#pragma unroll
        for (int off = 32; off > 0; off >>= 1) {
            dp += __shfl_xor(dp, off, 64);
            bs += __shfl_xor(bs, off, 64);
            ct += __shfl_xor(ct, off, 64);
        }
        if (tid == 0)
            gdpart[((size_t)side * NROWS + b) * 2 + half] =
                ct * lse[side * NROWS + b] - dp - bs;
    }
}

// ---------------------------------------------------------------------------
// Kernel 5: out = mean over b of sum of the 4 gdpart terms
__global__ void finalize_kernel(const float* __restrict__ gdpart, float* __restrict__ out) {
    __shared__ float r16[16];
    int i = threadIdx.x;   // 0..1023
    float v = gdpart[i * 2] + gdpart[i * 2 + 1]
            + gdpart[(NROWS + i) * 2] + gdpart[(NROWS + i) * 2 + 1];
#pragma unroll
    for (int off = 32; off > 0; off >>= 1) v += __shfl_xor(v, off, 64);
    if ((i & 63) == 0) r16[i >> 6] = v;
    __syncthreads();
    if (i < 64) {
        float x = (i < 16) ? r16[i] : 0.0f;
#pragma unroll
        for (int off = 8; off > 0; off >>= 1) x += __shfl_xor(x, off, 64);
        if (i == 0) out[0] = x * (1.0f / 1024.0f);
    }
}

// ---------------------------------------------------------------------------
extern "C" void kernel_launch(void* const* d_in, const int* in_sizes, int n_in,
                              void* d_out, int out_size, void* d_ws, size_t ws_size,
                              hipStream_t stream) {
    const float* z      = (const float*)d_in[0];
    const int*   tok_x  = (const int*)d_in[1];
    const int*   tok_y  = (const int*)d_in[2];
    const float* emb_x  = (const float*)d_in[3];
    const float* emb_y  = (const float*)d_in[4];
    const float* bias_x = (const float*)d_in[5];
    const float* bias_y = (const float*)d_in[6];
    float* out = (float*)d_out;

    char* ws = (char*)d_ws;
    const size_t ZBF_B  = 622592;                       // 38912 frags * 16 B
    const size_t PART_B = (size_t)2 * NCG * NROWS * 4;  // 12,845,056 B
    const size_t need   = ZBF_B + PART_B + 8192 + 16384;

    unsigned short* zbf = (unsigned short*)ws;
    zbf_kernel<<<152, 256, 0, stream>>>(z, zbf);

    if (ws_size >= need) {
        float* partial = (float*)(ws + ZBF_B);
        float* lse     = (float*)(ws + ZBF_B + PART_B);
        float* gdpart  = (float*)(ws + ZBF_B + PART_B + 8192);
        gemm_kernel<<<dim3(NBC, 2), 256, 0, stream>>>(zbf, emb_x, emb_y, bias_x, bias_y,
                                                      partial, lse /*unused*/, 0);
        lse_kernel<<<32, 1024, 0, stream>>>(partial, lse);
        gatherdot_kernel<<<dim3(NROWS, 4), 320, 0, stream>>>(z, tok_x, tok_y, emb_x, emb_y,
                                                             bias_x, bias_y, lse, gdpart);
        finalize_kernel<<<1, 1024, 0, stream>>>(gdpart, out);
    } else {
        // compact fallback: accumulate exp-sums with float atomics (error << tol)
        float* lse    = (float*)(ws + ZBF_B);
        float* gdpart = (float*)(ws + ZBF_B + 8192);
        hipMemsetAsync(lse, 0, 8192, stream);
        gemm_kernel<<<dim3(NBC, 2), 256, 0, stream>>>(zbf, emb_x, emb_y, bias_x, bias_y,
                                                      gdpart /*unused*/, lse, 1);
        lse_log_kernel<<<2, 1024, 0, stream>>>(lse);
        gatherdot_kernel<<<dim3(NROWS, 4), 320, 0, stream>>>(z, tok_x, tok_y, emb_x, emb_y,
                                                             bias_x, bias_y, lse, gdpart);
        finalize_kernel<<<1, 1024, 0, stream>>>(gdpart, out);
    }
}